// Round 1
// baseline (701.784 us; speedup 1.0000x reference)
//
#include <hip/hip_runtime.h>

// SchNet forward, MI355X. B=8,A=256,N=255,NB=NF=128,NG=25,NI=3,CUTOFF=5.
// Strategy: per-atom workgroup; pair filter-network (the 61-GFLOP core) on
// bf16 MFMA 16x16x32 with fp32 accum; everything else fp32.

#define NATOM 2048   // B*A
#define NNBR  255
#define NPAD  256

typedef __attribute__((ext_vector_type(8))) short bf16x8;  // 8 bf16 = 4 VGPR
typedef __attribute__((ext_vector_type(4))) float f32x4;

__device__ __forceinline__ unsigned short f2bf(float x){
  unsigned int u = __float_as_uint(x);
  u += 0x7fffu + ((u >> 16) & 1u);            // round-to-nearest-even
  return (unsigned short)(u >> 16);
}

__device__ __forceinline__ float sspf(float x){  // softplus(x) - ln2
  return fmaxf(x, 0.f) + log1pf(expf(-fabsf(x))) - 0.69314718055994530942f;
}

// ---------------------------------------------------------------- embeddings
__global__ void k_embed(const int* __restrict__ Z, const float* __restrict__ emb,
                        float* __restrict__ x){
  const int atom = blockIdx.x, t = threadIdx.x;
  x[atom*128 + t] = emb[Z[atom]*128 + t];
}

// ------------------------------------------------- distances + cutoff*mask S
__global__ void k_geom(const float* __restrict__ pos, const int* __restrict__ nbr,
                       const float* __restrict__ mask,
                       float* __restrict__ r_ws, float* __restrict__ S_ws){
  const int n = threadIdx.x, atom = blockIdx.x, molBase = atom & ~255;
  float r = 0.f, S = 0.f;
  if (n < NNBR){
    const int nb = nbr[atom*NNBR + n];
    const float ax = pos[atom*3+0], ay = pos[atom*3+1], az = pos[atom*3+2];
    const int pi = (molBase + nb)*3;
    const float dx = pos[pi+0]-ax, dy = pos[pi+1]-ay, dz = pos[pi+2]-az;
    r = sqrtf(dx*dx + dy*dy + dz*dz + 1e-12f);
    const float m = mask[atom*NNBR + n];
    r *= m;
    const float C = (r < 5.0f) ? 0.5f*(cosf(r*0.6283185307179586f)+1.0f) : 0.f;
    S = C * m;
  }
  r_ws[atom*NPAD + n] = r;   // padded slot n=255 -> r=0,S=0
  S_ws[atom*NPAD + n] = S;
}

// ------------------------- pre-transform fw1/fw2 into MFMA B-fragment order
// B-frag (16x16x32): lane l holds B[k=8*(l>>4)+j][col=16*n+(l&15)], j=0..7.
__global__ void k_prepw(const float* __restrict__ fw1, const float* __restrict__ fw2,
                        unsigned short* __restrict__ b1f, unsigned short* __restrict__ b2f){
  const int i = blockIdx.x, tid = threadIdx.x;
  const float* w1 = fw1 + i*25*128;
  const float* w2 = fw2 + i*128*128;
  unsigned short* o1 = b1f + i*8*64*8;
  unsigned short* o2 = b2f + i*32*64*8;
  for (int idx = tid; idx < 8*64; idx += 256){       // GEMM1 B: K=32 (25 padded), 8 N-tiles
    const int n = idx >> 6, l = idx & 63, khi = l >> 4, llo = l & 15;
    for (int j = 0; j < 8; ++j){
      const int g = khi*8 + j;
      o1[idx*8 + j] = f2bf((g < 25) ? w1[g*128 + n*16 + llo] : 0.f);
    }
  }
  for (int idx = tid; idx < 32*64; idx += 256){      // GEMM2 B: 4 K-steps x 8 N-tiles
    const int frag = idx >> 6, l = idx & 63;
    const int k0 = frag >> 3, n = frag & 7, khi = l >> 4, llo = l & 15;
    for (int j = 0; j < 8; ++j){
      const int k = k0*32 + khi*8 + j;
      o2[idx*8 + j] = f2bf(w2[k*128 + n*16 + llo]);
    }
  }
}

// ------------------------------------------------------------- y = x @ in2f
__global__ void k_y(const float* __restrict__ x, const float* __restrict__ w,
                    float* __restrict__ y){
  __shared__ float xs[128];
  const int t = threadIdx.x, atom = blockIdx.x;
  xs[t] = x[atom*128 + t];
  __syncthreads();
  float acc = 0.f;
  #pragma unroll 8
  for (int d = 0; d < 128; ++d) acc += xs[d] * w[d*128 + t];
  y[atom*128 + t] = acc;
}

// ------------------- the big fused kernel: filter net + cfconv + output MLP
__global__ __launch_bounds__(256, 2) void k_pairs(
    const float* __restrict__ r_ws, const float* __restrict__ S_ws,
    const int* __restrict__ nbr, const float* __restrict__ y,
    const unsigned short* __restrict__ b1f, const unsigned short* __restrict__ b2f,
    const float* __restrict__ fb1, const float* __restrict__ fb2,
    const float* __restrict__ w_f2out, const float* __restrict__ b_f2out,
    const float* __restrict__ w_dense, const float* __restrict__ b_dense,
    float* __restrict__ x){
  // LDS map (74KB -> 2 blocks/CU):
  //  [0,8K)    fs   : f_ij chunk, 128 rows x 32 bf16      (reduce phase: red 16x128 f32)
  //  [8K,40K)  Hs   : H chunk, 128 rows x 128 bf16, XOR-swizzled  (reuse: aggL/po/v1L)
  //  [40K,72K) B2s  : 32 GEMM2 B-frags x 64 lanes x 16B
  //  [72K,..)  Ss[256] f32, nbs[256] int
  __shared__ __align__(16) char smem[75776];
  unsigned short* fs  = (unsigned short*)smem;
  char*           Hsb = smem + 8*1024;
  unsigned short* B2s = (unsigned short*)(smem + 40*1024);
  float*          Ss  = (float*)(smem + 73728);
  int*            nbs = (int*)(smem + 74752);
  float*          red = (float*)smem;
  float*          aggL= (float*)(smem + 8192);
  float*          po  = (float*)(smem + 8704);
  float*          v1L = (float*)(smem + 9728);

  const int tid = threadIdx.x;
  const int wid = tid >> 6, lane = tid & 63, lhi = lane >> 4, llo = lane & 15;
  const int atom = blockIdx.x, molBase = atom & ~255;

  Ss[tid]  = S_ws[atom*NPAD + tid];
  nbs[tid] = (tid < NNBR) ? nbr[atom*NNBR + tid] : 0;
  { // B2 fragments -> LDS (coalesced 32KB copy)
    const float4* src = (const float4*)b2f;
    float4* dst = (float4*)B2s;
    #pragma unroll
    for (int k = 0; k < 8; ++k) dst[k*256 + tid] = src[k*256 + tid];
  }
  bf16x8 B1[8];
  #pragma unroll
  for (int n = 0; n < 8; ++n) B1[n] = *(const bf16x8*)(b1f + (n*64 + lane)*8);
  float b1b[8], b2b[8];
  #pragma unroll
  for (int n = 0; n < 8; ++n){ b1b[n] = fb1[n*16 + llo]; b2b[n] = fb2[n*16 + llo]; }

  float aggp[8];
  #pragma unroll
  for (int n = 0; n < 8; ++n) aggp[n] = 0.f;

  const float STEP = 5.0f/24.0f;
  const float GC   = -0.5f/(STEP*STEP);
  const f32x4 zero4 = {0.f,0.f,0.f,0.f};

  __syncthreads();

  for (int c = 0; c < 2; ++c){
    const int rowbase = c*128;
    { // stage f_ij chunk as bf16 (2 threads/row, 16 gaussians each)
      const int row = tid >> 1, half = tid & 1;
      const float r = r_ws[atom*NPAD + rowbase + row];
      #pragma unroll
      for (int gg = 0; gg < 16; ++gg){
        const int g = half*16 + gg;
        float v = 0.f;
        if (g < 25){ const float d = r - (float)g*STEP; v = expf(GC*d*d); }
        fs[row*32 + g] = f2bf(v);
      }
    }
    __syncthreads();

    // GEMM1: H = f_ij @ fw1  (single K=32 step), per-wave 32 rows x 128 cols
    bf16x8 a1[2];
    #pragma unroll
    for (int m = 0; m < 2; ++m){
      const int lrow = wid*32 + m*16 + llo;
      a1[m] = *(const bf16x8*)((const char*)fs + lrow*64 + lhi*16);
    }
    f32x4 h[2][8];
    #pragma unroll
    for (int m = 0; m < 2; ++m)
      #pragma unroll
      for (int n = 0; n < 8; ++n)
        h[m][n] = __builtin_amdgcn_mfma_f32_16x16x32_bf16(a1[m], B1[n], zero4, 0, 0, 0);

    // ssp epilogue (fp32) -> H bf16 into swizzled LDS (wave-local rows)
    #pragma unroll
    for (int m = 0; m < 2; ++m)
      #pragma unroll
      for (int n = 0; n < 8; ++n)
        #pragma unroll
        for (int j = 0; j < 4; ++j){
          const int lrow = wid*32 + m*16 + 4*lhi + j;
          const float hv = sspf(h[m][n][j] + b1b[n]);
          const int boff = (lrow*256 + (n*16 + llo)*2) ^ ((lrow & 7) << 4);
          *(unsigned short*)(Hsb + boff) = f2bf(hv);
        }

    // GEMM2: W = H @ fw2, K=128 in 4 steps
    f32x4 acc[2][8];
    #pragma unroll
    for (int m = 0; m < 2; ++m)
      #pragma unroll
      for (int n = 0; n < 8; ++n) acc[m][n] = zero4;
    #pragma unroll
    for (int k0 = 0; k0 < 4; ++k0){
      bf16x8 a2[2];
      #pragma unroll
      for (int m = 0; m < 2; ++m){
        const int lrow = wid*32 + m*16 + llo;
        const int boff = (lrow*256 + k0*64 + lhi*16) ^ ((lrow & 7) << 4);
        a2[m] = *(const bf16x8*)(Hsb + boff);
      }
      #pragma unroll
      for (int n = 0; n < 8; ++n){
        const bf16x8 b2 = *(const bf16x8*)((const char*)B2s + ((k0*8 + n)*64 + lane)*16);
        acc[0][n] = __builtin_amdgcn_mfma_f32_16x16x32_bf16(a2[0], b2, acc[0][n], 0, 0, 0);
        acc[1][n] = __builtin_amdgcn_mfma_f32_16x16x32_bf16(a2[1], b2, acc[1][n], 0, 0, 0);
      }
    }

    // aggregate: agg[f] += (W+b2)*S * y[nbr]  (fp32, gather from L2-resident y)
    #pragma unroll
    for (int m = 0; m < 2; ++m)
      #pragma unroll
      for (int j = 0; j < 4; ++j){
        const int lrow = wid*32 + m*16 + 4*lhi + j;
        const int grow = rowbase + lrow;
        const float S = Ss[grow];
        if (S != 0.f){
          const float* yrow = y + (molBase + nbs[grow])*128;
          #pragma unroll
          for (int n = 0; n < 8; ++n){
            const float w = acc[m][n][j] + b2b[n];
            aggp[n] += w * S * yrow[n*16 + llo];
          }
        }
      }
    __syncthreads();   // protects fs for next chunk / red reuse after loop
  }

  // cross-lane/wave reduction of agg (16 row-groups x 128 cols)
  #pragma unroll
  for (int n = 0; n < 8; ++n) red[(wid*4 + lhi)*128 + n*16 + llo] = aggp[n];
  __syncthreads();
  if (tid < 128){
    float s = 0.f;
    #pragma unroll
    for (int k = 0; k < 16; ++k) s += red[k*128 + tid];
    aggL[tid] = s;
  }
  __syncthreads();

  // fused output MLP (fp32): v = ssp(agg@f2out+b) @ dense + b ; x += v
  {
    const int f = tid & 127, hh = tid >> 7;
    float a1v = 0.f;
    #pragma unroll 8
    for (int t2 = 0; t2 < 64; ++t2){
      const int hidx = hh*64 + t2;
      a1v += aggL[hidx] * w_f2out[hidx*128 + f];
    }
    po[tid] = a1v;
    __syncthreads();
    if (tid < 128) v1L[tid] = sspf(po[tid] + po[tid + 128] + b_f2out[tid]);
    __syncthreads();
    float a2v = 0.f;
    #pragma unroll 8
    for (int t2 = 0; t2 < 64; ++t2){
      const int d = hh*64 + t2;
      a2v += v1L[d] * w_dense[d*128 + f];
    }
    po[tid] = a2v;
    __syncthreads();
    if (tid < 128) x[atom*128 + tid] += po[tid] + po[tid + 128] + b_dense[tid];
  }
}

// ---------------------------------------------------------------------------
extern "C" void kernel_launch(void* const* d_in, const int* in_sizes, int n_in,
                              void* d_out, int out_size, void* d_ws, size_t ws_size,
                              hipStream_t stream){
  const int*   Z    = (const int*)  d_in[0];
  const float* pos  = (const float*)d_in[1];
  const int*   nbr  = (const int*)  d_in[2];
  const float* mask = (const float*)d_in[3];
  const float* emb  = (const float*)d_in[4];
  const float* fw1  = (const float*)d_in[5];
  const float* fb1  = (const float*)d_in[6];
  const float* fw2  = (const float*)d_in[7];
  const float* fb2  = (const float*)d_in[8];
  const float* in2f = (const float*)d_in[9];
  const float* f2w  = (const float*)d_in[10];
  const float* f2b  = (const float*)d_in[11];
  const float* dw   = (const float*)d_in[12];
  const float* db   = (const float*)d_in[13];
  float* x = (float*)d_out;

  char* ws = (char*)d_ws;
  float* r_ws = (float*)ws;                                   // 2MB
  float* S_ws = (float*)(ws + NATOM*NPAD*4);                  // 2MB
  float* y    = (float*)(ws + 2*NATOM*NPAD*4);                // 1MB
  unsigned short* b1f = (unsigned short*)(ws + 2*NATOM*NPAD*4 + NATOM*128*4);
  unsigned short* b2f = b1f + 3*8*64*8;

  k_embed<<<NATOM, 128, 0, stream>>>(Z, emb, x);
  k_geom <<<NATOM, 256, 0, stream>>>(pos, nbr, mask, r_ws, S_ws);
  k_prepw<<<3,     256, 0, stream>>>(fw1, fw2, b1f, b2f);
  for (int i = 0; i < 3; ++i){
    k_y    <<<NATOM, 128, 0, stream>>>(x, in2f + i*128*128, y);
    k_pairs<<<NATOM, 256, 0, stream>>>(r_ws, S_ws, nbr, y,
        b1f + i*8*64*8, b2f + i*32*64*8,
        fb1 + i*128, fb2 + i*128,
        f2w + i*128*128, f2b + i*128, dw + i*128*128, db + i*128, x);
  }
}

// Round 2
// 173.771 us; speedup vs baseline: 4.0385x; 4.0385x over previous
//
#include <hip/hip_runtime.h>

// SchNet forward, MI355X. B=8,A=256,N=255,NB=NF=128,NG=25,NI=3,CUTOFF=5.
// R2: cutoff compaction (only ~29% of pairs are active) + hw transcendentals.

#define NATOM 2048   // B*A
#define NNBR  255

typedef __attribute__((ext_vector_type(8))) short bf16x8;  // 8 bf16 = 4 VGPR
typedef __attribute__((ext_vector_type(4))) float f32x4;

__device__ __forceinline__ unsigned short f2bf(float x){
  unsigned int u = __float_as_uint(x);
  u += 0x7fffu + ((u >> 16) & 1u);            // round-to-nearest-even
  return (unsigned short)(u >> 16);
}

// ssp(x) = softplus(x) - ln2 = ln(0.5*e^x + 0.5); |x| <~ 30 here, no overflow
__device__ __forceinline__ float sspf(float x){
  return __logf(fmaf(0.5f, __expf(x), 0.5f));
}

// ---------------------------------------------------------------- embeddings
__global__ void k_embed(const int* __restrict__ Z, const float* __restrict__ emb,
                        float* __restrict__ x){
  const int atom = blockIdx.x, t = threadIdx.x;
  x[atom*128 + t] = emb[Z[atom]*128 + t];
}

// ---------- geometry + deterministic compaction of active (S!=0) neighbors
__global__ void k_prep(const float* __restrict__ pos, const int* __restrict__ nbr,
                       const float* __restrict__ mask,
                       float* __restrict__ r_c, float* __restrict__ S_c,
                       int* __restrict__ nb_c, int* __restrict__ nact_g){
  __shared__ int wcnt[4];
  const int n = threadIdx.x, atom = blockIdx.x, molBase = atom & ~255;
  const int wid = n >> 6, lane = n & 63;
  float r = 0.f, S = 0.f; int nb = 0;
  if (n < NNBR){
    nb = nbr[atom*NNBR + n];
    const float ax = pos[atom*3+0], ay = pos[atom*3+1], az = pos[atom*3+2];
    const int pi = (molBase + nb)*3;
    const float dx = pos[pi+0]-ax, dy = pos[pi+1]-ay, dz = pos[pi+2]-az;
    r = sqrtf(dx*dx + dy*dy + dz*dz + 1e-12f);
    const float m = mask[atom*NNBR + n];
    r *= m;
    const float C = (r < 5.0f) ? 0.5f*(__cosf(r*0.6283185307179586f)+1.0f) : 0.f;
    S = C * m;
  }
  // zero-fill (padding rows must have S=0)
  r_c[atom*256 + n] = 0.f; S_c[atom*256 + n] = 0.f; nb_c[atom*256 + n] = 0;
  const unsigned long long b = __ballot(S != 0.f);
  const int rank = __popcll(b & ((1ull << lane) - 1ull));
  if (lane == 0) wcnt[wid] = __popcll(b);
  __syncthreads();                 // wcnt ready AND zero-fill done
  int off = 0;
  for (int w = 0; w < 4; ++w) if (w < wid) off += wcnt[w];
  if (S != 0.f){
    const int slot = off + rank;
    r_c[atom*256 + slot] = r; S_c[atom*256 + slot] = S; nb_c[atom*256 + slot] = nb;
  }
  if (n == 0) nact_g[atom] = wcnt[0] + wcnt[1] + wcnt[2] + wcnt[3];
}

// ------------------------- pre-transform fw1/fw2 into MFMA B-fragment order
// B-frag (16x16x32): lane l holds B[k=8*(l>>4)+j][col=16*n+(l&15)], j=0..7.
__global__ void k_prepw(const float* __restrict__ fw1, const float* __restrict__ fw2,
                        unsigned short* __restrict__ b1f, unsigned short* __restrict__ b2f){
  const int i = blockIdx.x, tid = threadIdx.x;
  const float* w1 = fw1 + i*25*128;
  const float* w2 = fw2 + i*128*128;
  unsigned short* o1 = b1f + i*8*64*8;
  unsigned short* o2 = b2f + i*32*64*8;
  for (int idx = tid; idx < 8*64; idx += 256){       // GEMM1 B: K=32 (25 padded)
    const int n = idx >> 6, l = idx & 63, khi = l >> 4, llo = l & 15;
    for (int j = 0; j < 8; ++j){
      const int g = khi*8 + j;
      o1[idx*8 + j] = f2bf((g < 25) ? w1[g*128 + n*16 + llo] : 0.f);
    }
  }
  for (int idx = tid; idx < 32*64; idx += 256){      // GEMM2 B: 4 K-steps x 8 N-tiles
    const int frag = idx >> 6, l = idx & 63;
    const int k0 = frag >> 3, n = frag & 7, khi = l >> 4, llo = l & 15;
    for (int j = 0; j < 8; ++j){
      const int k = k0*32 + khi*8 + j;
      o2[idx*8 + j] = f2bf(w2[k*128 + n*16 + llo]);
    }
  }
}

// ------------------------------------------------------------- y = x @ in2f
__global__ void k_y(const float* __restrict__ x, const float* __restrict__ w,
                    float* __restrict__ y){
  __shared__ float xs[128];
  const int t = threadIdx.x, atom = blockIdx.x;
  xs[t] = x[atom*128 + t];
  __syncthreads();
  float acc = 0.f;
  #pragma unroll 8
  for (int d = 0; d < 128; ++d) acc += xs[d] * w[d*128 + t];
  y[atom*128 + t] = acc;
}

// ------------------- fused: filter net (MFMA) + cfconv agg + output MLP
__global__ __launch_bounds__(256, 3) void k_pairs(
    const float* __restrict__ r_c, const float* __restrict__ S_c,
    const int* __restrict__ nb_c, const int* __restrict__ nact_g,
    const float* __restrict__ y,
    const unsigned short* __restrict__ b1f, const unsigned short* __restrict__ b2f,
    const float* __restrict__ fb1, const float* __restrict__ fb2,
    const float* __restrict__ w_f2out, const float* __restrict__ b_f2out,
    const float* __restrict__ w_dense, const float* __restrict__ b_dense,
    float* __restrict__ x){
  // LDS (50KB -> 3 blocks/CU):
  //  [0,32K)   B2s : 32 GEMM2 B-frags x 64 lanes x 16B
  //  [32K,48K) Hw  : per-wave 16x128 bf16 H buffer, XOR-swizzled (4KB/wave)
  //            (reused as red[16][128] f32 after compute loop)
  //  [48K,50K) aggL[128] f32, po[256] f32, v1L[128] f32
  __shared__ __align__(16) char smem[51200];
  unsigned short* B2s = (unsigned short*)smem;
  float* red  = (float*)(smem + 32768);
  float* aggL = (float*)(smem + 49152);
  float* po   = (float*)(smem + 49152 + 512);
  float* v1L  = (float*)(smem + 49152 + 1536);

  const int tid = threadIdx.x;
  const int wid = tid >> 6, lane = tid & 63, lhi = lane >> 4, llo = lane & 15;
  const int atom = blockIdx.x, molBase = atom & ~255;
  char* Hw = smem + 32768 + wid*4096;

  { // B2 fragments -> LDS (coalesced 32KB copy)
    const float4* src = (const float4*)b2f;
    float4* dst = (float4*)B2s;
    #pragma unroll
    for (int k = 0; k < 8; ++k) dst[k*256 + tid] = src[k*256 + tid];
  }
  bf16x8 B1[8];
  #pragma unroll
  for (int n = 0; n < 8; ++n) B1[n] = *(const bf16x8*)(b1f + (n*64 + lane)*8);
  float b1b[8], b2b[8];
  #pragma unroll
  for (int n = 0; n < 8; ++n){ b1b[n] = fb1[n*16 + llo]; b2b[n] = fb2[n*16 + llo]; }

  const int nact = nact_g[atom];
  const int ntiles = (nact + 15) >> 4;

  float aggp[8];
  #pragma unroll
  for (int n = 0; n < 8; ++n) aggp[n] = 0.f;

  const float STEP = 5.0f/24.0f;
  const float GC   = -11.52f;              // -0.5/STEP^2 = -288/25
  const f32x4 zero4 = {0.f,0.f,0.f,0.f};

  __syncthreads();                         // B2s ready

  // waves round-robin over 16-row tiles of active neighbors; fully wave-local
  for (int t = wid; t < ntiles; t += 4){
    const int row0 = t*16;
    // A1 fragment in-register: f[row0+llo][g=8*lhi+jj]
    const float r = r_c[atom*256 + row0 + llo];
    bf16x8 a1;
    #pragma unroll
    for (int jj = 0; jj < 8; ++jj){
      const int g = lhi*8 + jj;
      float v = 0.f;
      if (g < 25){ const float d = r - (float)g*STEP; v = __expf(GC*d*d); }
      a1[jj] = (short)f2bf(v);
    }
    // GEMM1: H(16x128) = f @ fw1
    f32x4 h[8];
    #pragma unroll
    for (int n = 0; n < 8; ++n)
      h[n] = __builtin_amdgcn_mfma_f32_16x16x32_bf16(a1, B1[n], zero4, 0, 0, 0);
    // ssp -> bf16 into wave-local swizzled LDS (transpose for GEMM2 A-frag)
    #pragma unroll
    for (int n = 0; n < 8; ++n)
      #pragma unroll
      for (int j = 0; j < 4; ++j){
        const int lrow = 4*lhi + j;
        const float hv = sspf(h[n][j] + b1b[n]);
        const int boff = (lrow*256 + (n*16 + llo)*2) ^ ((lrow & 7) << 4);
        *(unsigned short*)(Hw + boff) = f2bf(hv);
      }
    // GEMM2: W(16x128) = H @ fw2, K=128 in 4 steps
    f32x4 acc[8];
    #pragma unroll
    for (int n = 0; n < 8; ++n) acc[n] = zero4;
    #pragma unroll
    for (int k0 = 0; k0 < 4; ++k0){
      const int boff = (llo*256 + k0*64 + lhi*16) ^ ((llo & 7) << 4);
      const bf16x8 a2 = *(const bf16x8*)(Hw + boff);
      #pragma unroll
      for (int n = 0; n < 8; ++n){
        const bf16x8 b2 = *(const bf16x8*)(B2s + ((k0*8 + n)*64 + lane)*8);
        acc[n] = __builtin_amdgcn_mfma_f32_16x16x32_bf16(a2, b2, acc[n], 0, 0, 0);
      }
    }
    // aggregate: agg[f] += (W+b2)*S * y[nbr]
    #pragma unroll
    for (int j = 0; j < 4; ++j){
      const int grow = row0 + 4*lhi + j;
      const float S = S_c[atom*256 + grow];
      const float* yrow = y + (molBase + nb_c[atom*256 + grow])*128;
      #pragma unroll
      for (int n = 0; n < 8; ++n)
        aggp[n] = fmaf((acc[n][j] + b2b[n]) * S, yrow[n*16 + llo], aggp[n]);
    }
  }

  __syncthreads();                         // all waves done; Hw region -> red
  #pragma unroll
  for (int n = 0; n < 8; ++n) red[(wid*4 + lhi)*128 + n*16 + llo] = aggp[n];
  __syncthreads();
  if (tid < 128){
    float s = 0.f;
    #pragma unroll
    for (int k = 0; k < 16; ++k) s += red[k*128 + tid];
    aggL[tid] = s;
  }
  __syncthreads();

  // fused output MLP (fp32): v = ssp(agg@f2out+b) @ dense + b ; x += v
  {
    const int f = tid & 127, hh = tid >> 7;
    float a1v = 0.f;
    #pragma unroll 8
    for (int t2 = 0; t2 < 64; ++t2){
      const int hidx = hh*64 + t2;
      a1v += aggL[hidx] * w_f2out[hidx*128 + f];
    }
    po[tid] = a1v;
    __syncthreads();
    if (tid < 128) v1L[tid] = sspf(po[tid] + po[tid + 128] + b_f2out[tid]);
    __syncthreads();
    float a2v = 0.f;
    #pragma unroll 8
    for (int t2 = 0; t2 < 64; ++t2){
      const int d = hh*64 + t2;
      a2v += v1L[d] * w_dense[d*128 + f];
    }
    po[tid] = a2v;
    __syncthreads();
    if (tid < 128) x[atom*128 + tid] += po[tid] + po[tid + 128] + b_dense[tid];
  }
}

// ---------------------------------------------------------------------------
extern "C" void kernel_launch(void* const* d_in, const int* in_sizes, int n_in,
                              void* d_out, int out_size, void* d_ws, size_t ws_size,
                              hipStream_t stream){
  const int*   Z    = (const int*)  d_in[0];
  const float* pos  = (const float*)d_in[1];
  const int*   nbr  = (const int*)  d_in[2];
  const float* mask = (const float*)d_in[3];
  const float* emb  = (const float*)d_in[4];
  const float* fw1  = (const float*)d_in[5];
  const float* fb1  = (const float*)d_in[6];
  const float* fw2  = (const float*)d_in[7];
  const float* fb2  = (const float*)d_in[8];
  const float* in2f = (const float*)d_in[9];
  const float* f2w  = (const float*)d_in[10];
  const float* f2b  = (const float*)d_in[11];
  const float* dw   = (const float*)d_in[12];
  const float* db   = (const float*)d_in[13];
  float* x = (float*)d_out;

  char* ws = (char*)d_ws;
  float* y    = (float*)ws;                              // 1MB
  float* r_c  = (float*)(ws + 1*1024*1024);              // 2MB
  float* S_c  = (float*)(ws + 3*1024*1024);              // 2MB
  int*   nb_c = (int*)  (ws + 5*1024*1024);              // 2MB
  int*   nact = (int*)  (ws + 7*1024*1024);              // 8KB
  unsigned short* b1f = (unsigned short*)(ws + 7*1024*1024 + 16*1024);
  unsigned short* b2f = b1f + 3*8*64*8;

  k_embed<<<NATOM, 128, 0, stream>>>(Z, emb, x);
  k_prep <<<NATOM, 256, 0, stream>>>(pos, nbr, mask, r_c, S_c, nb_c, nact);
  k_prepw<<<3,     256, 0, stream>>>(fw1, fw2, b1f, b2f);
  for (int i = 0; i < 3; ++i){
    k_y    <<<NATOM, 128, 0, stream>>>(x, in2f + i*128*128, y);
    k_pairs<<<NATOM, 256, 0, stream>>>(r_c, S_c, nb_c, nact, y,
        b1f + i*8*64*8, b2f + i*32*64*8,
        fb1 + i*128, fb2 + i*128,
        f2w + i*128*128, f2b + i*128, dw + i*128*128, db + i*128, x);
  }
}